// Round 2
// baseline (730.541 us; speedup 1.0000x reference)
//
#include <hip/hip_runtime.h>

typedef unsigned short u16;
typedef unsigned int u32;
using bf16x8  = __attribute__((ext_vector_type(8))) __bf16;
using u16x8   = __attribute__((ext_vector_type(8), may_alias)) u16;
using f32x4   = __attribute__((ext_vector_type(4))) float;
using f32x4_a = __attribute__((ext_vector_type(4), may_alias)) float;

#define DEV __device__ __forceinline__

constexpr int Bn = 4, Hn = 4, Nn = 2048, Mn = 2048, Dn = 64, DIMn = 256;
constexpr float SCALEc = 0.125f;   // 64^-0.5
constexpr float SHIFTc = 12.0f;    // fixed softmax shift (max logit ~6; overflow needs >100)

DEV float bf2f(u16 h) { u32 u = ((u32)h) << 16; return __builtin_bit_cast(float, u); }
DEV u16 f2bf(float f) {
    u32 u = __builtin_bit_cast(u32, f);
    u += 0x7fffu + ((u >> 16) & 1u);   // RNE
    return (u16)(u >> 16);
}
DEV bf16x8 ld8bf(const u16* p) {
    return __builtin_bit_cast(bf16x8, *reinterpret_cast<const u16x8*>(p));
}
DEV bf16x8 ld8f_bf(const float* p) {
    const f32x4 a = *reinterpret_cast<const f32x4_a*>(p);
    const f32x4 b = *reinterpret_cast<const f32x4_a*>(p + 4);
    u16x8 r;
    r[0] = f2bf(a[0]); r[1] = f2bf(a[1]); r[2] = f2bf(a[2]); r[3] = f2bf(a[3]);
    r[4] = f2bf(b[0]); r[5] = f2bf(b[1]); r[6] = f2bf(b[2]); r[7] = f2bf(b[3]);
    return __builtin_bit_cast(bf16x8, r);
}

// ---------------------------------------------------------------------------
// Q projection: Q = x_query @ Wq^T + bq  ->  fp32 (B,H,N,D)
// ---------------------------------------------------------------------------
__global__ __launch_bounds__(256) void qproj_kernel(
    const float* __restrict__ X, const float* __restrict__ W,
    const float* __restrict__ bias, float* __restrict__ Q)
{
    const int row0 = blockIdx.x * 32;
    const int wave = threadIdx.x >> 6, lane = threadIdx.x & 63;
    const int quad = lane >> 4, l16 = lane & 15;
    const int o0 = wave * 64;
    const int b = row0 >> 11, n0 = row0 & 2047;

    f32x4 acc[2][4] = {};
    #pragma unroll
    for (int k0 = 0; k0 < 256; k0 += 32) {
        bf16x8 af[2], wf[4];
        #pragma unroll
        for (int ns = 0; ns < 2; ns++)
            af[ns] = ld8f_bf(X + (size_t)(row0 + ns * 16 + l16) * DIMn + k0 + quad * 8);
        #pragma unroll
        for (int os = 0; os < 4; os++)
            wf[os] = ld8f_bf(W + (size_t)(o0 + os * 16 + l16) * DIMn + k0 + quad * 8);
        #pragma unroll
        for (int ns = 0; ns < 2; ns++)
            #pragma unroll
            for (int os = 0; os < 4; os++)
                acc[ns][os] = __builtin_amdgcn_mfma_f32_16x16x32_bf16(af[ns], wf[os], acc[ns][os], 0, 0, 0);
    }
    #pragma unroll
    for (int os = 0; os < 4; os++) {
        const int col = o0 + os * 16 + l16;
        const int h = col >> 6, d = col & 63;
        const float bb = bias[col];
        #pragma unroll
        for (int ns = 0; ns < 2; ns++)
            #pragma unroll
            for (int r = 0; r < 4; r++) {
                const int n = n0 + ns * 16 + quad * 4 + r;
                Q[((size_t)(b * Hn + h) * Nn + n) * Dn + d] = acc[ns][os][r] + bb;
            }
    }
}

// ---------------------------------------------------------------------------
// Fused K/V projection: K -> bf16 (B,H,M,D); V -> bf16 (B,H,D,M) transposed.
// ---------------------------------------------------------------------------
__global__ __launch_bounds__(256) void kvproj_kernel(
    const float* __restrict__ X,
    const float* __restrict__ Wk, const float* __restrict__ bk,
    const float* __restrict__ Wv, const float* __restrict__ bv,
    u16* __restrict__ K, u16* __restrict__ V)
{
    const int row0 = blockIdx.x * 32;
    const int wave = threadIdx.x >> 6, lane = threadIdx.x & 63;
    const int quad = lane >> 4, l16 = lane & 15;
    const int o0 = wave * 64;
    const int b = row0 >> 11, n0 = row0 & 2047;

    f32x4 ack[2][4] = {};
    f32x4 acv[4][2] = {};
    #pragma unroll
    for (int k0 = 0; k0 < 256; k0 += 32) {
        bf16x8 af[2], wkf[4], wvf[4];
        #pragma unroll
        for (int ns = 0; ns < 2; ns++)
            af[ns] = ld8f_bf(X + (size_t)(row0 + ns * 16 + l16) * DIMn + k0 + quad * 8);
        #pragma unroll
        for (int os = 0; os < 4; os++) {
            wkf[os] = ld8f_bf(Wk + (size_t)(o0 + os * 16 + l16) * DIMn + k0 + quad * 8);
            wvf[os] = ld8f_bf(Wv + (size_t)(o0 + os * 16 + l16) * DIMn + k0 + quad * 8);
        }
        #pragma unroll
        for (int ns = 0; ns < 2; ns++)
            #pragma unroll
            for (int os = 0; os < 4; os++) {
                ack[ns][os] = __builtin_amdgcn_mfma_f32_16x16x32_bf16(af[ns], wkf[os], ack[ns][os], 0, 0, 0);
                // A = Wv rows (feature), B = X^T (X's A-frag == X^T's B-frag)
                acv[os][ns] = __builtin_amdgcn_mfma_f32_16x16x32_bf16(wvf[os], af[ns], acv[os][ns], 0, 0, 0);
            }
    }
    #pragma unroll
    for (int os = 0; os < 4; os++) {
        const int col = o0 + os * 16 + l16;
        const int h = col >> 6, d = col & 63;
        const float bb = bk[col];
        #pragma unroll
        for (int ns = 0; ns < 2; ns++)
            #pragma unroll
            for (int r = 0; r < 4; r++) {
                const int m = n0 + ns * 16 + quad * 4 + r;
                K[((size_t)(b * Hn + h) * Mn + m) * Dn + d] = f2bf(ack[ns][os][r] + bb);
            }
    }
    #pragma unroll
    for (int os = 0; os < 4; os++)
        #pragma unroll
        for (int r = 0; r < 4; r++) {
            const int colf = o0 + os * 16 + quad * 4 + r;
            const int h = colf >> 6, d = colf & 63;
            const float bb = bv[colf];
            #pragma unroll
            for (int ns = 0; ns < 2; ns++) {
                const int m = n0 + ns * 16 + l16;
                V[((size_t)(b * Hn + h) * Dn + d) * Mn + m] = f2bf(acv[os][ns][r] + bb);
            }
        }
}

// ---------------------------------------------------------------------------
// Flash attention with fp32 geo bias; fixed shift, no barriers.
// Grid (N/64, H, B); block 256 thr = 4 waves; wave owns 16 Q-rows.
// ---------------------------------------------------------------------------
__global__ __launch_bounds__(256) void attn_kernel(
    const float* __restrict__ Q,   // (B,H,N,D) fp32
    const u16* __restrict__ K,     // (B,H,M,D) bf16
    const u16* __restrict__ V,     // (B,H,D,M) bf16
    const float* __restrict__ geo, // (B,H,N,M) fp32
    u16* __restrict__ AO)          // (B*N, 256) bf16
{
    __shared__ __align__(16) u16 lds[4][16 * 136];

    const int h = blockIdx.y, b = blockIdx.z;
    const int wave = threadIdx.x >> 6, lane = threadIdx.x & 63;
    const int quad = lane >> 4, l16 = lane & 15;
    const int nbase = blockIdx.x * 64 + wave * 16;

    const float* Qh = Q + ((size_t)(b * Hn + h) * Nn + nbase) * Dn;
    const u16*   Kh = K + (size_t)(b * Hn + h) * Mn * Dn;
    const u16*   Vh = V + (size_t)(b * Hn + h) * Dn * Mn;
    const float* Gh = geo + ((size_t)(b * Hn + h) * Nn + nbase) * (size_t)Mn;

    bf16x8 qh[2], ql[2];
    #pragma unroll
    for (int kh = 0; kh < 2; kh++) {
        const float* qp = Qh + (size_t)l16 * Dn + kh * 32 + quad * 8;
        const f32x4 a = *reinterpret_cast<const f32x4_a*>(qp);
        const f32x4 c = *reinterpret_cast<const f32x4_a*>(qp + 4);
        u16x8 hi, lo;
        #pragma unroll
        for (int j = 0; j < 4; j++) {
            hi[j] = f2bf(a[j]); lo[j] = f2bf(a[j] - bf2f(hi[j]));
            hi[4 + j] = f2bf(c[j]); lo[4 + j] = f2bf(c[j] - bf2f(hi[4 + j]));
        }
        qh[kh] = __builtin_bit_cast(bf16x8, hi);
        ql[kh] = __builtin_bit_cast(bf16x8, lo);
    }

    f32x4 oacc[4] = {};
    float lsum[4] = {0.f, 0.f, 0.f, 0.f};
    u16* pl = &lds[wave][0];

    for (int m0 = 0; m0 < Mn; m0 += 128) {
        #pragma unroll
        for (int ms = 0; ms < 8; ms++) {
            const int mc = m0 + ms * 16 + l16;
            const u16* kp = Kh + (size_t)mc * Dn + quad * 8;
            const bf16x8 kb0 = ld8bf(kp);
            const bf16x8 kb1 = ld8bf(kp + 32);
            f32x4 s = {};
            s = __builtin_amdgcn_mfma_f32_16x16x32_bf16(qh[0], kb0, s, 0, 0, 0);
            s = __builtin_amdgcn_mfma_f32_16x16x32_bf16(ql[0], kb0, s, 0, 0, 0);
            s = __builtin_amdgcn_mfma_f32_16x16x32_bf16(qh[1], kb1, s, 0, 0, 0);
            s = __builtin_amdgcn_mfma_f32_16x16x32_bf16(ql[1], kb1, s, 0, 0, 0);
            #pragma unroll
            for (int r = 0; r < 4; r++) {
                const float g = Gh[(size_t)(quad * 4 + r) * Mn + mc];
                const float p = __expf(fmaf(s[r], SCALEc, g) - SHIFTc);
                lsum[r] += p;
                pl[(quad * 4 + r) * 136 + ms * 16 + l16] = f2bf(p);
            }
        }
        #pragma unroll
        for (int kk = 0; kk < 4; kk++) {
            const bf16x8 pa = ld8bf(pl + l16 * 136 + kk * 32 + quad * 8);
            #pragma unroll
            for (int ds = 0; ds < 4; ds++) {
                const bf16x8 vb = ld8bf(Vh + (size_t)(ds * 16 + l16) * Mn + m0 + kk * 32 + quad * 8);
                oacc[ds] = __builtin_amdgcn_mfma_f32_16x16x32_bf16(pa, vb, oacc[ds], 0, 0, 0);
            }
        }
    }

    u16* AOr = AO + ((size_t)b * Nn + nbase) * DIMn + h * Dn;
    #pragma unroll
    for (int r = 0; r < 4; r++) {
        float rs = lsum[r];
        rs += __shfl_xor(rs, 1);
        rs += __shfl_xor(rs, 2);
        rs += __shfl_xor(rs, 4);
        rs += __shfl_xor(rs, 8);
        const float inv = 1.0f / rs;
        #pragma unroll
        for (int ds = 0; ds < 4; ds++)
            AOr[(size_t)(quad * 4 + r) * DIMn + ds * 16 + l16] = f2bf(oacc[ds][r] * inv);
    }
}

// ---------------------------------------------------------------------------
// Output projection: out = AO @ Wo^T + bo -> fp32 (B*N, 256)
// ---------------------------------------------------------------------------
__global__ __launch_bounds__(256) void oproj_kernel(
    const u16* __restrict__ A, const float* __restrict__ W,
    const float* __restrict__ bias, float* __restrict__ out)
{
    const int row0 = blockIdx.x * 32;
    const int wave = threadIdx.x >> 6, lane = threadIdx.x & 63;
    const int quad = lane >> 4, l16 = lane & 15;
    const int o0 = wave * 64;

    f32x4 acc[2][4] = {};
    #pragma unroll
    for (int k0 = 0; k0 < 256; k0 += 32) {
        bf16x8 af[2], wf[4];
        #pragma unroll
        for (int ns = 0; ns < 2; ns++)
            af[ns] = ld8bf(A + (size_t)(row0 + ns * 16 + l16) * DIMn + k0 + quad * 8);
        #pragma unroll
        for (int os = 0; os < 4; os++)
            wf[os] = ld8f_bf(W + (size_t)(o0 + os * 16 + l16) * DIMn + k0 + quad * 8);
        #pragma unroll
        for (int ns = 0; ns < 2; ns++)
            #pragma unroll
            for (int os = 0; os < 4; os++)
                acc[ns][os] = __builtin_amdgcn_mfma_f32_16x16x32_bf16(af[ns], wf[os], acc[ns][os], 0, 0, 0);
    }
    #pragma unroll
    for (int os = 0; os < 4; os++) {
        const int col = o0 + os * 16 + l16;
        const float bb = bias[col];
        #pragma unroll
        for (int ns = 0; ns < 2; ns++)
            #pragma unroll
            for (int r = 0; r < 4; r++) {
                const int row = row0 + ns * 16 + quad * 4 + r;
                out[(size_t)row * DIMn + col] = acc[ns][os][r] + bb;
            }
    }
}

// ---------------------------------------------------------------------------
extern "C" void kernel_launch(void* const* d_in, const int* in_sizes, int n_in,
                              void* d_out, int out_size, void* d_ws, size_t ws_size,
                              hipStream_t stream) {
    const float* xq  = (const float*)d_in[0];
    const float* xc  = (const float*)d_in[1];
    const float* geo = (const float*)d_in[2];
    const float* Wq  = (const float*)d_in[3];
    const float* bq  = (const float*)d_in[4];
    const float* Wk  = (const float*)d_in[5];
    const float* bk  = (const float*)d_in[6];
    const float* Wv  = (const float*)d_in[7];
    const float* bv  = (const float*)d_in[8];
    const float* Wo  = (const float*)d_in[9];
    const float* bo  = (const float*)d_in[10];

    char* ws = (char*)d_ws;
    float* Qw  = (float*)ws;                          // 8 MB fp32 (B,H,N,D)
    u16*   Kw  = (u16*)(ws + 8388608);                // 4 MB bf16 (B,H,M,D)
    u16*   Vw  = (u16*)(ws + 8388608 + 4194304);      // 4 MB bf16 (B,H,D,M)
    u16*   AOw = (u16*)(ws + 8388608 + 2 * 4194304);  // 4 MB bf16 (B*N, 256)

    qproj_kernel<<<256, 256, 0, stream>>>(xq, Wq, bq, Qw);
    kvproj_kernel<<<256, 256, 0, stream>>>(xc, Wk, bk, Wv, bv, Kw, Vw);
    attn_kernel<<<dim3(Nn / 64, Hn, Bn), 256, 0, stream>>>(Qw, Kw, Vw, geo, AOw);
    oproj_kernel<<<256, 256, 0, stream>>>(AOw, Wo, bo, (float*)d_out);
}

// Round 3
// 583.093 us; speedup vs baseline: 1.2529x; 1.2529x over previous
//
#include <hip/hip_runtime.h>

typedef unsigned short u16;
typedef unsigned int u32;
using bf16x8  = __attribute__((ext_vector_type(8))) __bf16;
using u16x8   = __attribute__((ext_vector_type(8), may_alias)) u16;
using u16x4   = __attribute__((ext_vector_type(4), may_alias)) u16;
using f32x4   = __attribute__((ext_vector_type(4))) float;
using f32x4_a = __attribute__((ext_vector_type(4), may_alias)) float;

#define DEV __device__ __forceinline__

constexpr int Bn = 4, Hn = 4, Nn = 2048, Mn = 2048, Dn = 64, DIMn = 256;
constexpr float SCALEc = 0.125f;   // 64^-0.5
constexpr float SHIFTc = 12.0f;    // fixed softmax shift (max logit ~6; overflow needs >100)

DEV float bf2f(u16 h) { u32 u = ((u32)h) << 16; return __builtin_bit_cast(float, u); }
DEV u16 f2bf(float f) {
    u32 u = __builtin_bit_cast(u32, f);
    u += 0x7fffu + ((u >> 16) & 1u);   // RNE
    return (u16)(u >> 16);
}
DEV bf16x8 ld8bf(const u16* p) {
    return __builtin_bit_cast(bf16x8, *reinterpret_cast<const u16x8*>(p));
}
DEV bf16x8 ld8f_bf(const float* p) {
    const f32x4 a = *reinterpret_cast<const f32x4_a*>(p);
    const f32x4 b = *reinterpret_cast<const f32x4_a*>(p + 4);
    u16x8 r;
    r[0] = f2bf(a[0]); r[1] = f2bf(a[1]); r[2] = f2bf(a[2]); r[3] = f2bf(a[3]);
    r[4] = f2bf(b[0]); r[5] = f2bf(b[1]); r[6] = f2bf(b[2]); r[7] = f2bf(b[3]);
    return __builtin_bit_cast(bf16x8, r);
}

// ---------------------------------------------------------------------------
// Q projection: Q = x_query @ Wq^T + bq  ->  fp32 (B,H,N,D)
// ---------------------------------------------------------------------------
__global__ __launch_bounds__(256) void qproj_kernel(
    const float* __restrict__ X, const float* __restrict__ W,
    const float* __restrict__ bias, float* __restrict__ Q)
{
    const int row0 = blockIdx.x * 32;
    const int wave = threadIdx.x >> 6, lane = threadIdx.x & 63;
    const int quad = lane >> 4, l16 = lane & 15;
    const int o0 = wave * 64;
    const int b = row0 >> 11, n0 = row0 & 2047;

    f32x4 acc[2][4] = {};
    #pragma unroll
    for (int k0 = 0; k0 < 256; k0 += 32) {
        bf16x8 af[2], wf[4];
        #pragma unroll
        for (int ns = 0; ns < 2; ns++)
            af[ns] = ld8f_bf(X + (size_t)(row0 + ns * 16 + l16) * DIMn + k0 + quad * 8);
        #pragma unroll
        for (int os = 0; os < 4; os++)
            wf[os] = ld8f_bf(W + (size_t)(o0 + os * 16 + l16) * DIMn + k0 + quad * 8);
        #pragma unroll
        for (int ns = 0; ns < 2; ns++)
            #pragma unroll
            for (int os = 0; os < 4; os++)
                acc[ns][os] = __builtin_amdgcn_mfma_f32_16x16x32_bf16(af[ns], wf[os], acc[ns][os], 0, 0, 0);
    }
    #pragma unroll
    for (int os = 0; os < 4; os++) {
        const int col = o0 + os * 16 + l16;
        const int h = col >> 6, d = col & 63;
        const float bb = bias[col];
        #pragma unroll
        for (int ns = 0; ns < 2; ns++)
            #pragma unroll
            for (int r = 0; r < 4; r++) {
                const int n = n0 + ns * 16 + quad * 4 + r;
                Q[((size_t)(b * Hn + h) * Nn + n) * Dn + d] = acc[ns][os][r] + bb;
            }
    }
}

// ---------------------------------------------------------------------------
// Fused K/V projection: K -> bf16 (B,H,M,D); V -> bf16 (B,H,D,M) transposed.
// ---------------------------------------------------------------------------
__global__ __launch_bounds__(256) void kvproj_kernel(
    const float* __restrict__ X,
    const float* __restrict__ Wk, const float* __restrict__ bk,
    const float* __restrict__ Wv, const float* __restrict__ bv,
    u16* __restrict__ K, u16* __restrict__ V)
{
    const int row0 = blockIdx.x * 32;
    const int wave = threadIdx.x >> 6, lane = threadIdx.x & 63;
    const int quad = lane >> 4, l16 = lane & 15;
    const int o0 = wave * 64;
    const int b = row0 >> 11, n0 = row0 & 2047;

    f32x4 ack[2][4] = {};
    f32x4 acv[4][2] = {};
    #pragma unroll
    for (int k0 = 0; k0 < 256; k0 += 32) {
        bf16x8 af[2], wkf[4], wvf[4];
        #pragma unroll
        for (int ns = 0; ns < 2; ns++)
            af[ns] = ld8f_bf(X + (size_t)(row0 + ns * 16 + l16) * DIMn + k0 + quad * 8);
        #pragma unroll
        for (int os = 0; os < 4; os++) {
            wkf[os] = ld8f_bf(Wk + (size_t)(o0 + os * 16 + l16) * DIMn + k0 + quad * 8);
            wvf[os] = ld8f_bf(Wv + (size_t)(o0 + os * 16 + l16) * DIMn + k0 + quad * 8);
        }
        #pragma unroll
        for (int ns = 0; ns < 2; ns++)
            #pragma unroll
            for (int os = 0; os < 4; os++) {
                ack[ns][os] = __builtin_amdgcn_mfma_f32_16x16x32_bf16(af[ns], wkf[os], ack[ns][os], 0, 0, 0);
                // A = Wv rows (feature), B = X^T (X's A-frag == X^T's B-frag)
                acv[os][ns] = __builtin_amdgcn_mfma_f32_16x16x32_bf16(wvf[os], af[ns], acv[os][ns], 0, 0, 0);
            }
    }
    #pragma unroll
    for (int os = 0; os < 4; os++) {
        const int col = o0 + os * 16 + l16;
        const int h = col >> 6, d = col & 63;
        const float bb = bk[col];
        #pragma unroll
        for (int ns = 0; ns < 2; ns++)
            #pragma unroll
            for (int r = 0; r < 4; r++) {
                const int m = n0 + ns * 16 + quad * 4 + r;
                K[((size_t)(b * Hn + h) * Mn + m) * Dn + d] = f2bf(ack[ns][os][r] + bb);
            }
    }
    #pragma unroll
    for (int os = 0; os < 4; os++)
        #pragma unroll
        for (int r = 0; r < 4; r++) {
            const int colf = o0 + os * 16 + quad * 4 + r;
            const int h = colf >> 6, d = colf & 63;
            const float bb = bv[colf];
            #pragma unroll
            for (int ns = 0; ns < 2; ns++) {
                const int m = n0 + ns * 16 + l16;
                V[((size_t)(b * Hn + h) * Dn + d) * Mn + m] = f2bf(acv[os][ns][r] + bb);
            }
        }
}

// ---------------------------------------------------------------------------
// Flash attention, TRANSPOSED score tiles: S^T = K Q^T via mfma(A=K, B=Q^T).
// C-layout of S^T: lane (quad,l16) holds rows m=quad*4+r, col n=l16.
//  -> geo[n][m] is 4 consecutive m's: one dwordx4 load per (ms) per lane.
//  -> lsum is a single per-lane scalar (col n), 2 shuffles at the end.
//  -> P^T packs to one ds_write_b64 per (ms); PV reads A-frags ds_read_b128.
// LDS row stride 144 (u16): row shift = 8 banks -> conflict-free b64/b128.
// No barriers (wave-private LDS, in-order DS pipe). Grid (N/64, H, B).
// ---------------------------------------------------------------------------
__global__ __launch_bounds__(256) void attn_kernel(
    const float* __restrict__ Q,   // (B,H,N,D) fp32
    const u16* __restrict__ K,     // (B,H,M,D) bf16
    const u16* __restrict__ V,     // (B,H,D,M) bf16
    const float* __restrict__ geo, // (B,H,N,M) fp32
    u16* __restrict__ AO)          // (B*N, 256) bf16
{
    __shared__ __align__(16) u16 lds[4][2][16 * 144];

    const int h = blockIdx.y, b = blockIdx.z;
    const int wave = threadIdx.x >> 6, lane = threadIdx.x & 63;
    const int quad = lane >> 4, l16 = lane & 15;
    const int nbase = blockIdx.x * 64 + wave * 16;

    const float* Qh = Q + ((size_t)(b * Hn + h) * Nn + nbase) * Dn;
    const u16*   Kh = K + (size_t)(b * Hn + h) * Mn * Dn;
    const u16*   Vh = V + (size_t)(b * Hn + h) * Dn * Mn;
    // this lane's geo row: n = nbase + l16
    const float* Gl = geo + ((size_t)(b * Hn + h) * Nn + nbase + l16) * (size_t)Mn;

    // Q^T B-fragments (hi/lo split for compensated QK^T)
    bf16x8 qh[2], ql[2];
    #pragma unroll
    for (int kh = 0; kh < 2; kh++) {
        const float* qp = Qh + (size_t)l16 * Dn + kh * 32 + quad * 8;
        const f32x4 a = *reinterpret_cast<const f32x4_a*>(qp);
        const f32x4 c = *reinterpret_cast<const f32x4_a*>(qp + 4);
        u16x8 hi, lo;
        #pragma unroll
        for (int j = 0; j < 4; j++) {
            hi[j] = f2bf(a[j]); lo[j] = f2bf(a[j] - bf2f(hi[j]));
            hi[4 + j] = f2bf(c[j]); lo[4 + j] = f2bf(c[j] - bf2f(hi[4 + j]));
        }
        qh[kh] = __builtin_bit_cast(bf16x8, hi);
        ql[kh] = __builtin_bit_cast(bf16x8, lo);
    }

    f32x4 oacc[4] = {};
    float lsum = 0.f;

    for (int m0 = 0; m0 < Mn; m0 += 128) {
        u16* pl = &lds[wave][(m0 >> 7) & 1][0];
        #pragma unroll
        for (int ms = 0; ms < 8; ms++) {
            const int mb = m0 + ms * 16;
            const u16* kp = Kh + (size_t)(mb + l16) * Dn + quad * 8;
            const bf16x8 kb0 = ld8bf(kp);
            const bf16x8 kb1 = ld8bf(kp + 32);
            f32x4 s = {};
            s = __builtin_amdgcn_mfma_f32_16x16x32_bf16(kb0, qh[0], s, 0, 0, 0);
            s = __builtin_amdgcn_mfma_f32_16x16x32_bf16(kb0, ql[0], s, 0, 0, 0);
            s = __builtin_amdgcn_mfma_f32_16x16x32_bf16(kb1, qh[1], s, 0, 0, 0);
            s = __builtin_amdgcn_mfma_f32_16x16x32_bf16(kb1, ql[1], s, 0, 0, 0);
            const f32x4 g = *reinterpret_cast<const f32x4_a*>(Gl + mb + quad * 4);
            u16x4 pk;
            float ls = 0.f;
            #pragma unroll
            for (int r = 0; r < 4; r++) {
                const float p = __expf(fmaf(s[r], SCALEc, g[r]) - SHIFTc);
                ls += p;
                pk[r] = f2bf(p);
            }
            lsum += ls;
            // P stored as [n=l16][m]: lane writes 4 consecutive m's -> b64
            *reinterpret_cast<u16x4*>(pl + l16 * 144 + ms * 16 + quad * 4) = pk;
        }
        // O += P V : P A-frags (ds_read_b128), V^T B-frags (global 16B)
        #pragma unroll
        for (int kh = 0; kh < 4; kh++) {
            const bf16x8 pa = ld8bf(pl + l16 * 144 + kh * 32 + quad * 8);
            #pragma unroll
            for (int ds = 0; ds < 4; ds++) {
                const bf16x8 vb = ld8bf(Vh + (size_t)(ds * 16 + l16) * Mn + m0 + kh * 32 + quad * 8);
                oacc[ds] = __builtin_amdgcn_mfma_f32_16x16x32_bf16(pa, vb, oacc[ds], 0, 0, 0);
            }
        }
    }

    // lsum currently: per-lane partial over this quad's m's, col n=l16.
    lsum += __shfl_xor(lsum, 16);
    lsum += __shfl_xor(lsum, 32);   // now: full sum for col n=l16, all lanes

    u16* AOr = AO + ((size_t)b * Nn + nbase) * DIMn + h * Dn;
    #pragma unroll
    for (int r = 0; r < 4; r++) {
        // epilogue row n = quad*4+r; its lsum lives in lane (quad*4+r)
        const float inv = 1.0f / __shfl(lsum, quad * 4 + r);
        #pragma unroll
        for (int ds = 0; ds < 4; ds++)
            AOr[(size_t)(quad * 4 + r) * DIMn + ds * 16 + l16] = f2bf(oacc[ds][r] * inv);
    }
}

// ---------------------------------------------------------------------------
// Output projection: out = AO @ Wo^T + bo -> fp32 (B*N, 256)
// ---------------------------------------------------------------------------
__global__ __launch_bounds__(256) void oproj_kernel(
    const u16* __restrict__ A, const float* __restrict__ W,
    const float* __restrict__ bias, float* __restrict__ out)
{
    const int row0 = blockIdx.x * 32;
    const int wave = threadIdx.x >> 6, lane = threadIdx.x & 63;
    const int quad = lane >> 4, l16 = lane & 15;
    const int o0 = wave * 64;

    f32x4 acc[2][4] = {};
    #pragma unroll
    for (int k0 = 0; k0 < 256; k0 += 32) {
        bf16x8 af[2], wf[4];
        #pragma unroll
        for (int ns = 0; ns < 2; ns++)
            af[ns] = ld8bf(A + (size_t)(row0 + ns * 16 + l16) * DIMn + k0 + quad * 8);
        #pragma unroll
        for (int os = 0; os < 4; os++)
            wf[os] = ld8f_bf(W + (size_t)(o0 + os * 16 + l16) * DIMn + k0 + quad * 8);
        #pragma unroll
        for (int ns = 0; ns < 2; ns++)
            #pragma unroll
            for (int os = 0; os < 4; os++)
                acc[ns][os] = __builtin_amdgcn_mfma_f32_16x16x32_bf16(af[ns], wf[os], acc[ns][os], 0, 0, 0);
    }
    #pragma unroll
    for (int os = 0; os < 4; os++) {
        const int col = o0 + os * 16 + l16;
        const float bb = bias[col];
        #pragma unroll
        for (int ns = 0; ns < 2; ns++)
            #pragma unroll
            for (int r = 0; r < 4; r++) {
                const int row = row0 + ns * 16 + quad * 4 + r;
                out[(size_t)row * DIMn + col] = acc[ns][os][r] + bb;
            }
    }
}

// ---------------------------------------------------------------------------
extern "C" void kernel_launch(void* const* d_in, const int* in_sizes, int n_in,
                              void* d_out, int out_size, void* d_ws, size_t ws_size,
                              hipStream_t stream) {
    const float* xq  = (const float*)d_in[0];
    const float* xc  = (const float*)d_in[1];
    const float* geo = (const float*)d_in[2];
    const float* Wq  = (const float*)d_in[3];
    const float* bq  = (const float*)d_in[4];
    const float* Wk  = (const float*)d_in[5];
    const float* bk  = (const float*)d_in[6];
    const float* Wv  = (const float*)d_in[7];
    const float* bv  = (const float*)d_in[8];
    const float* Wo  = (const float*)d_in[9];
    const float* bo  = (const float*)d_in[10];

    char* ws = (char*)d_ws;
    float* Qw  = (float*)ws;                          // 8 MB fp32 (B,H,N,D)
    u16*   Kw  = (u16*)(ws + 8388608);                // 4 MB bf16 (B,H,M,D)
    u16*   Vw  = (u16*)(ws + 8388608 + 4194304);      // 4 MB bf16 (B,H,D,M)
    u16*   AOw = (u16*)(ws + 8388608 + 2 * 4194304);  // 4 MB bf16 (B*N, 256)

    qproj_kernel<<<256, 256, 0, stream>>>(xq, Wq, bq, Qw);
    kvproj_kernel<<<256, 256, 0, stream>>>(xc, Wk, bk, Wv, bv, Kw, Vw);
    attn_kernel<<<dim3(Nn / 64, Hn, Bn), 256, 0, stream>>>(Qw, Kw, Vw, geo, AOw);
    oproj_kernel<<<256, 256, 0, stream>>>(AOw, Wo, bo, (float*)d_out);
}

// Round 4
// 556.291 us; speedup vs baseline: 1.3132x; 1.0482x over previous
//
#include <hip/hip_runtime.h>

typedef unsigned short u16;
typedef unsigned int u32;
using bf16x8  = __attribute__((ext_vector_type(8))) __bf16;
using u16x8   = __attribute__((ext_vector_type(8), may_alias)) u16;
using u16x4   = __attribute__((ext_vector_type(4), may_alias)) u16;
using f32x4   = __attribute__((ext_vector_type(4))) float;
using f32x4_a = __attribute__((ext_vector_type(4), may_alias)) float;

#define DEV __device__ __forceinline__

constexpr int Bn = 4, Hn = 4, Nn = 2048, Mn = 2048, Dn = 64, DIMn = 256;
constexpr float SCALEc = 0.125f;   // 64^-0.5
constexpr float SHIFTc = 12.0f;    // fixed softmax shift (max logit ~6; overflow needs >100)
constexpr int LSTRIDE = 152;       // u16; 76 dwords, 76%32=12 -> conflict-free b64/b128

DEV float bf2f(u16 h) { u32 u = ((u32)h) << 16; return __builtin_bit_cast(float, u); }
DEV u16 f2bf(float f) {
    u32 u = __builtin_bit_cast(u32, f);
    u += 0x7fffu + ((u >> 16) & 1u);   // RNE
    return (u16)(u >> 16);
}
DEV bf16x8 ld8bf(const u16* p) {
    return __builtin_bit_cast(bf16x8, *reinterpret_cast<const u16x8*>(p));
}
DEV bf16x8 ld8f_bf(const float* p) {
    const f32x4 a = *reinterpret_cast<const f32x4_a*>(p);
    const f32x4 b = *reinterpret_cast<const f32x4_a*>(p + 4);
    u16x8 r;
    r[0] = f2bf(a[0]); r[1] = f2bf(a[1]); r[2] = f2bf(a[2]); r[3] = f2bf(a[3]);
    r[4] = f2bf(b[0]); r[5] = f2bf(b[1]); r[6] = f2bf(b[2]); r[7] = f2bf(b[3]);
    return __builtin_bit_cast(bf16x8, r);
}

// ---------------------------------------------------------------------------
// Q projection: Q = x_query @ Wq^T + bq  ->  fp32 (B,H,N,D)
// ---------------------------------------------------------------------------
__global__ __launch_bounds__(256) void qproj_kernel(
    const float* __restrict__ X, const float* __restrict__ W,
    const float* __restrict__ bias, float* __restrict__ Q)
{
    const int row0 = blockIdx.x * 32;
    const int wave = threadIdx.x >> 6, lane = threadIdx.x & 63;
    const int quad = lane >> 4, l16 = lane & 15;
    const int o0 = wave * 64;
    const int b = row0 >> 11, n0 = row0 & 2047;

    f32x4 acc[2][4] = {};
    #pragma unroll
    for (int k0 = 0; k0 < 256; k0 += 32) {
        bf16x8 af[2], wf[4];
        #pragma unroll
        for (int ns = 0; ns < 2; ns++)
            af[ns] = ld8f_bf(X + (size_t)(row0 + ns * 16 + l16) * DIMn + k0 + quad * 8);
        #pragma unroll
        for (int os = 0; os < 4; os++)
            wf[os] = ld8f_bf(W + (size_t)(o0 + os * 16 + l16) * DIMn + k0 + quad * 8);
        #pragma unroll
        for (int ns = 0; ns < 2; ns++)
            #pragma unroll
            for (int os = 0; os < 4; os++)
                acc[ns][os] = __builtin_amdgcn_mfma_f32_16x16x32_bf16(af[ns], wf[os], acc[ns][os], 0, 0, 0);
    }
    #pragma unroll
    for (int os = 0; os < 4; os++) {
        const int col = o0 + os * 16 + l16;
        const int h = col >> 6, d = col & 63;
        const float bb = bias[col];
        #pragma unroll
        for (int ns = 0; ns < 2; ns++)
            #pragma unroll
            for (int r = 0; r < 4; r++) {
                const int n = n0 + ns * 16 + quad * 4 + r;
                Q[((size_t)(b * Hn + h) * Nn + n) * Dn + d] = acc[ns][os][r] + bb;
            }
    }
}

// ---------------------------------------------------------------------------
// Fused K/V projection: K -> bf16 (B,H,M,D); V -> bf16 (B,H,D,M) transposed.
// ---------------------------------------------------------------------------
__global__ __launch_bounds__(256) void kvproj_kernel(
    const float* __restrict__ X,
    const float* __restrict__ Wk, const float* __restrict__ bk,
    const float* __restrict__ Wv, const float* __restrict__ bv,
    u16* __restrict__ K, u16* __restrict__ V)
{
    const int row0 = blockIdx.x * 32;
    const int wave = threadIdx.x >> 6, lane = threadIdx.x & 63;
    const int quad = lane >> 4, l16 = lane & 15;
    const int o0 = wave * 64;
    const int b = row0 >> 11, n0 = row0 & 2047;

    f32x4 ack[2][4] = {};
    f32x4 acv[4][2] = {};
    #pragma unroll
    for (int k0 = 0; k0 < 256; k0 += 32) {
        bf16x8 af[2], wkf[4], wvf[4];
        #pragma unroll
        for (int ns = 0; ns < 2; ns++)
            af[ns] = ld8f_bf(X + (size_t)(row0 + ns * 16 + l16) * DIMn + k0 + quad * 8);
        #pragma unroll
        for (int os = 0; os < 4; os++) {
            wkf[os] = ld8f_bf(Wk + (size_t)(o0 + os * 16 + l16) * DIMn + k0 + quad * 8);
            wvf[os] = ld8f_bf(Wv + (size_t)(o0 + os * 16 + l16) * DIMn + k0 + quad * 8);
        }
        #pragma unroll
        for (int ns = 0; ns < 2; ns++)
            #pragma unroll
            for (int os = 0; os < 4; os++) {
                ack[ns][os] = __builtin_amdgcn_mfma_f32_16x16x32_bf16(af[ns], wkf[os], ack[ns][os], 0, 0, 0);
                acv[os][ns] = __builtin_amdgcn_mfma_f32_16x16x32_bf16(wvf[os], af[ns], acv[os][ns], 0, 0, 0);
            }
    }
    #pragma unroll
    for (int os = 0; os < 4; os++) {
        const int col = o0 + os * 16 + l16;
        const int h = col >> 6, d = col & 63;
        const float bb = bk[col];
        #pragma unroll
        for (int ns = 0; ns < 2; ns++)
            #pragma unroll
            for (int r = 0; r < 4; r++) {
                const int m = n0 + ns * 16 + quad * 4 + r;
                K[((size_t)(b * Hn + h) * Mn + m) * Dn + d] = f2bf(ack[ns][os][r] + bb);
            }
    }
    #pragma unroll
    for (int os = 0; os < 4; os++)
        #pragma unroll
        for (int r = 0; r < 4; r++) {
            const int colf = o0 + os * 16 + quad * 4 + r;
            const int h = colf >> 6, d = colf & 63;
            const float bb = bv[colf];
            #pragma unroll
            for (int ns = 0; ns < 2; ns++) {
                const int m = n0 + ns * 16 + l16;
                V[((size_t)(b * Hn + h) * Dn + d) * Mn + m] = f2bf(acv[os][ns][r] + bb);
            }
        }
}

// ---------------------------------------------------------------------------
// Flash attention, split-M, transposed score tiles (S^T = K Q^T).
// Grid (N/64, H, B*S). Block 256 thr = 4 waves; wave owns 16 Q-rows and
// M-range [split*Mn/S, (split+1)*Mn/S). Fixed softmax shift -> split partials
// (numerator, lsum) are directly addable; combine_kernel normalizes.
// Single-buffer wave-private LDS (in-order DS pipe), stride 152 -> no
// conflicts. No barriers.
// ---------------------------------------------------------------------------
__global__ __launch_bounds__(256) void attn_kernel(
    const float* __restrict__ Q,    // (B,H,N,D) fp32
    const u16* __restrict__ K,      // (B,H,M,D) bf16
    const u16* __restrict__ V,      // (B,H,D,M) bf16
    const float* __restrict__ geo,  // (B,H,N,M) fp32
    float* __restrict__ Pnum,       // (S, B*N, 256) fp32 numerator partials
    float* __restrict__ Lsum,       // (S, B, H, N) fp32 denominator partials
    int S)
{
    __shared__ __align__(16) u16 lds[4][16 * LSTRIDE];

    const int h = blockIdx.y;
    const int b = blockIdx.z / S, split = blockIdx.z % S;
    const int wave = threadIdx.x >> 6, lane = threadIdx.x & 63;
    const int quad = lane >> 4, l16 = lane & 15;
    const int nbase = blockIdx.x * 64 + wave * 16;
    const int mlen = Mn / S, mbeg = split * mlen;

    const float* Qh = Q + ((size_t)(b * Hn + h) * Nn + nbase) * Dn;
    const u16*   Kh = K + (size_t)(b * Hn + h) * Mn * Dn;
    const u16*   Vh = V + (size_t)(b * Hn + h) * Dn * Mn;
    const float* Gl = geo + ((size_t)(b * Hn + h) * Nn + nbase + l16) * (size_t)Mn;

    // Q^T B-fragments (hi/lo split for compensated QK^T)
    bf16x8 qh[2], ql[2];
    #pragma unroll
    for (int kh = 0; kh < 2; kh++) {
        const float* qp = Qh + (size_t)l16 * Dn + kh * 32 + quad * 8;
        const f32x4 a = *reinterpret_cast<const f32x4_a*>(qp);
        const f32x4 c = *reinterpret_cast<const f32x4_a*>(qp + 4);
        u16x8 hi, lo;
        #pragma unroll
        for (int j = 0; j < 4; j++) {
            hi[j] = f2bf(a[j]); lo[j] = f2bf(a[j] - bf2f(hi[j]));
            hi[4 + j] = f2bf(c[j]); lo[4 + j] = f2bf(c[j] - bf2f(hi[4 + j]));
        }
        qh[kh] = __builtin_bit_cast(bf16x8, hi);
        ql[kh] = __builtin_bit_cast(bf16x8, lo);
    }

    f32x4 oacc[4] = {};
    float lsum = 0.f;
    u16* pl = &lds[wave][0];

    for (int m0 = mbeg; m0 < mbeg + mlen; m0 += 128) {
        #pragma unroll
        for (int ms = 0; ms < 8; ms++) {
            const int mb = m0 + ms * 16;
            const u16* kp = Kh + (size_t)(mb + l16) * Dn + quad * 8;
            const bf16x8 kb0 = ld8bf(kp);
            const bf16x8 kb1 = ld8bf(kp + 32);
            f32x4 s = {};
            s = __builtin_amdgcn_mfma_f32_16x16x32_bf16(kb0, qh[0], s, 0, 0, 0);
            s = __builtin_amdgcn_mfma_f32_16x16x32_bf16(kb0, ql[0], s, 0, 0, 0);
            s = __builtin_amdgcn_mfma_f32_16x16x32_bf16(kb1, qh[1], s, 0, 0, 0);
            s = __builtin_amdgcn_mfma_f32_16x16x32_bf16(kb1, ql[1], s, 0, 0, 0);
            const f32x4 g = *reinterpret_cast<const f32x4_a*>(Gl + mb + quad * 4);
            u16x4 pk;
            float ls = 0.f;
            #pragma unroll
            for (int r = 0; r < 4; r++) {
                const float p = __expf(fmaf(s[r], SCALEc, g[r]) - SHIFTc);
                ls += p;
                pk[r] = f2bf(p);
            }
            lsum += ls;
            *reinterpret_cast<u16x4*>(pl + l16 * LSTRIDE + ms * 16 + quad * 4) = pk;
        }
        #pragma unroll
        for (int kh = 0; kh < 4; kh++) {
            const bf16x8 pa = ld8bf(pl + l16 * LSTRIDE + kh * 32 + quad * 8);
            #pragma unroll
            for (int ds = 0; ds < 4; ds++) {
                const bf16x8 vb = ld8bf(Vh + (size_t)(ds * 16 + l16) * Mn + (m0 - mbeg) + mbeg + kh * 32 + quad * 8);
                oacc[ds] = __builtin_amdgcn_mfma_f32_16x16x32_bf16(pa, vb, oacc[ds], 0, 0, 0);
            }
        }
    }

    // reduce lsum across quads: all lanes end with full sum for col n=l16
    lsum += __shfl_xor(lsum, 16);
    lsum += __shfl_xor(lsum, 32);

    // write numerator partial (AO layout, per-split slab) and lsum partial
    float* PN = Pnum + (size_t)split * (Bn * (size_t)Nn * DIMn)
                     + ((size_t)b * Nn + nbase) * DIMn + h * Dn;
    #pragma unroll
    for (int r = 0; r < 4; r++)
        #pragma unroll
        for (int ds = 0; ds < 4; ds++)
            PN[(size_t)(quad * 4 + r) * DIMn + ds * 16 + l16] = oacc[ds][r];

    if (lane < 16)
        Lsum[(((size_t)split * Bn + b) * Hn + h) * Nn + nbase + l16] = lsum;
}

// ---------------------------------------------------------------------------
// Combine: AO = sum_s Pnum[s] / sum_s Lsum[s]  -> bf16 (B*N, 256)
// One thread per 8 consecutive columns.
// ---------------------------------------------------------------------------
__global__ __launch_bounds__(256) void combine_kernel(
    const float* __restrict__ Pnum, const float* __restrict__ Lsum,
    u16* __restrict__ AO, int S)
{
    const int idx = blockIdx.x * 256 + threadIdx.x;    // [0, B*N*32)
    const int row = idx >> 5;                          // b*Nn + n
    const int c0  = (idx & 31) * 8;
    const int b = row >> 11, n = row & 2047, h = c0 >> 6;

    float l = 0.f;
    for (int s = 0; s < S; s++)
        l += Lsum[(((size_t)s * Bn + b) * Hn + h) * Nn + n];
    const float inv = 1.0f / l;

    f32x4 a0 = {}, a1 = {};
    for (int s = 0; s < S; s++) {
        const float* p = Pnum + (size_t)s * (Bn * (size_t)Nn * DIMn) + (size_t)row * DIMn + c0;
        a0 += *reinterpret_cast<const f32x4_a*>(p);
        a1 += *reinterpret_cast<const f32x4_a*>(p + 4);
    }
    u16x8 o;
    #pragma unroll
    for (int j = 0; j < 4; j++) {
        o[j]     = f2bf(a0[j] * inv);
        o[4 + j] = f2bf(a1[j] * inv);
    }
    *reinterpret_cast<u16x8*>(AO + (size_t)row * DIMn + c0) = o;
}

// ---------------------------------------------------------------------------
// Output projection: out = AO @ Wo^T + bo -> fp32 (B*N, 256)
// ---------------------------------------------------------------------------
__global__ __launch_bounds__(256) void oproj_kernel(
    const u16* __restrict__ A, const float* __restrict__ W,
    const float* __restrict__ bias, float* __restrict__ out)
{
    const int row0 = blockIdx.x * 32;
    const int wave = threadIdx.x >> 6, lane = threadIdx.x & 63;
    const int quad = lane >> 4, l16 = lane & 15;
    const int o0 = wave * 64;

    f32x4 acc[2][4] = {};
    #pragma unroll
    for (int k0 = 0; k0 < 256; k0 += 32) {
        bf16x8 af[2], wf[4];
        #pragma unroll
        for (int ns = 0; ns < 2; ns++)
            af[ns] = ld8bf(A + (size_t)(row0 + ns * 16 + l16) * DIMn + k0 + quad * 8);
        #pragma unroll
        for (int os = 0; os < 4; os++)
            wf[os] = ld8f_bf(W + (size_t)(o0 + os * 16 + l16) * DIMn + k0 + quad * 8);
        #pragma unroll
        for (int ns = 0; ns < 2; ns++)
            #pragma unroll
            for (int os = 0; os < 4; os++)
                acc[ns][os] = __builtin_amdgcn_mfma_f32_16x16x32_bf16(af[ns], wf[os], acc[ns][os], 0, 0, 0);
    }
    #pragma unroll
    for (int os = 0; os < 4; os++) {
        const int col = o0 + os * 16 + l16;
        const float bb = bias[col];
        #pragma unroll
        for (int ns = 0; ns < 2; ns++)
            #pragma unroll
            for (int r = 0; r < 4; r++) {
                const int row = row0 + ns * 16 + quad * 4 + r;
                out[(size_t)row * DIMn + col] = acc[ns][os][r] + bb;
            }
    }
}

// ---------------------------------------------------------------------------
extern "C" void kernel_launch(void* const* d_in, const int* in_sizes, int n_in,
                              void* d_out, int out_size, void* d_ws, size_t ws_size,
                              hipStream_t stream) {
    const float* xq  = (const float*)d_in[0];
    const float* xc  = (const float*)d_in[1];
    const float* geo = (const float*)d_in[2];
    const float* Wq  = (const float*)d_in[3];
    const float* bq  = (const float*)d_in[4];
    const float* Wk  = (const float*)d_in[5];
    const float* bk  = (const float*)d_in[6];
    const float* Wv  = (const float*)d_in[7];
    const float* bv  = (const float*)d_in[8];
    const float* Wo  = (const float*)d_in[9];
    const float* bo  = (const float*)d_in[10];

    const int S = (ws_size >= (60ull << 20)) ? 4 : 1;

    char* ws = (char*)d_ws;
    float* Qw   = (float*)ws;                              // 8 MB fp32 (B,H,N,D)
    u16*   Kw   = (u16*)(ws + (8ull << 20));               // 4 MB bf16 (B,H,M,D)
    u16*   Vw   = (u16*)(ws + (12ull << 20));              // 4 MB bf16 (B,H,D,M)
    u16*   AOw  = (u16*)(ws + (16ull << 20));              // 4 MB bf16 (B*N, 256)
    float* Pnum = (float*)(ws + (20ull << 20));            // S x 8 MB fp32
    float* Lsum = (float*)(ws + (20ull << 20) + (size_t)S * (8ull << 20));  // S x 128 KB

    qproj_kernel<<<256, 256, 0, stream>>>(xq, Wq, bq, Qw);
    kvproj_kernel<<<256, 256, 0, stream>>>(xc, Wk, bk, Wv, bv, Kw, Vw);
    attn_kernel<<<dim3(Nn / 64, Hn, Bn * S), 256, 0, stream>>>(Qw, Kw, Vw, geo, Pnum, Lsum, S);
    combine_kernel<<<(Bn * Nn * 32) / 256, 256, 0, stream>>>(Pnum, Lsum, AOw, S);
    oproj_kernel<<<256, 256, 0, stream>>>(AOw, Wo, bo, (float*)d_out);
}